// Round 1
// baseline (314.731 us; speedup 1.0000x reference)
//
#include <hip/hip_runtime.h>

typedef __attribute__((ext_vector_type(8))) short s16x8;
typedef __attribute__((ext_vector_type(8))) unsigned short u16x8;
typedef __attribute__((ext_vector_type(4))) float f32x4;
typedef unsigned short u16;
typedef unsigned int u32;

#define T_ 2048
#define C_ 512
#define H_ 8
#define DKP 96
#define LOG2E 1.44269504088896340736f

__device__ __forceinline__ u16 f2b(float f) {
  u32 u = __float_as_uint(f);
  return (u16)((u + 0x7FFFu + ((u >> 16) & 1u)) >> 16);
}

__device__ __forceinline__ u16x8 cvt8(float4 a, float4 b) {
  u16x8 o;
  o[0] = f2b(a.x); o[1] = f2b(a.y); o[2] = f2b(a.z); o[3] = f2b(a.w);
  o[4] = f2b(b.x); o[5] = f2b(b.y); o[6] = f2b(b.z); o[7] = f2b(b.w);
  return o;
}

__device__ __forceinline__ f32x4 mfma16(s16x8 a, s16x8 b, f32x4 c) {
  return __builtin_amdgcn_mfma_f32_16x16x32_bf16(a, b, c, 0, 0, 0);
}

// ---------------------------------------------------------------------------
// Convert/pack: xb, Wcat(Wq|Wk|Wv), Wo16, bcat(fp32), Q pad cols (onehot q%3),
// K pad cols (bias[c][k%3]).  Block regions:
//  [0,2048) xb  [2048,2432) wcat  [2432,2560) wo16  [2560] bcat
//  [2561,3585) Qpad  [3585,4609) Kpad
// ---------------------------------------------------------------------------
__global__ __launch_bounds__(256) void k_convert(
    const float* __restrict__ x,
    const float* __restrict__ wq, const float* __restrict__ wk,
    const float* __restrict__ wv, const float* __restrict__ wo,
    const float* __restrict__ bq, const float* __restrict__ bk,
    const float* __restrict__ bv, const float* __restrict__ pb,
    u16* __restrict__ xb, u16* __restrict__ wcat, u16* __restrict__ wo16,
    float* __restrict__ bcat, u16* __restrict__ qp, u16* __restrict__ kp)
{
  const int blk = blockIdx.x, tid = threadIdx.x;
  if (blk < 2048) {
    int i = blk * 2048 + tid * 8;
    float4 a = *(const float4*)(x + i);
    float4 b = *(const float4*)(x + i + 4);
    *(u16x8*)(xb + i) = cvt8(a, b);
  } else if (blk < 2432) {
    int bi = blk - 2048;
    const float* src; int off;
    if (bi < 128)      { src = wq; off = bi * 2048; }
    else if (bi < 256) { src = wk; off = (bi - 128) * 2048; }
    else               { src = wv; off = (bi - 256) * 2048; }
    int i = off + tid * 8;
    float4 a = *(const float4*)(src + i);
    float4 b = *(const float4*)(src + i + 4);
    *(u16x8*)(wcat + bi * 2048 + tid * 8) = cvt8(a, b);
  } else if (blk < 2560) {
    int i = (blk - 2432) * 2048 + tid * 8;
    float4 a = *(const float4*)(wo + i);
    float4 b = *(const float4*)(wo + i + 4);
    *(u16x8*)(wo16 + i) = cvt8(a, b);
  } else if (blk == 2560) {
    if (tid < 192) {
      int i = tid * 8;
      const float* src; int off;
      if (i < 512)       { src = bq; off = i; }
      else if (i < 1024) { src = bk; off = i - 512; }
      else               { src = bv; off = i - 1024; }
      *(float4*)(bcat + i)     = *(const float4*)(src + off);
      *(float4*)(bcat + i + 4) = *(const float4*)(src + off + 4);
    }
  } else if (blk < 3585) {
    int e = (blk - 2561) * 2048 + tid * 8;
    int row = e >> 5, cc = e & 31;
    int tp = (row & 2047) % 3;
    u16x8 o;
    #pragma unroll
    for (int j = 0; j < 8; ++j) {
      int cidx = cc + j;
      o[j] = (cidx < 3) ? ((tp == cidx) ? (u16)0x3F80 : (u16)0) : (u16)0;
    }
    *(u16x8*)(qp + row * DKP + 64 + cc) = o;
  } else {
    int e = (blk - 3585) * 2048 + tid * 8;
    int row = e >> 5, cc = e & 31;
    int tp = (row & 2047) % 3;
    u16x8 o;
    #pragma unroll
    for (int j = 0; j < 8; ++j) {
      int cidx = cc + j;
      o[j] = (cidx < 3) ? f2b(pb[cidx * 3 + tp]) : (u16)0;
    }
    *(u16x8*)(kp + row * DKP + 64 + cc) = o;
  }
}

// ---------------------------------------------------------------------------
// GEMM  C[m][n] = A[m][:] . B[n][:] + bias[n]   (A,B bf16 K-contig, K=512)
// BM=BN=128, BK=32, 4 waves (2x2), each wave 64x64 (4x4 frags of 16x16x32).
// MODE 0: QKV — route tiles to Qp (scaled 0.125, [bh][t][96]), Kp, Vtmp.
// MODE 1: O-proj — fp32 out [8192][512].
// ---------------------------------------------------------------------------
template<int MODE>
__global__ __launch_bounds__(256) void k_gemm(
    const u16* __restrict__ A, const u16* __restrict__ Bw,
    const float* __restrict__ bias,
    u16* __restrict__ qp, u16* __restrict__ kp, u16* __restrict__ vtmp,
    float* __restrict__ yout)
{
  const int n0 = blockIdx.x * 128;
  const int m0 = blockIdx.y * 128;
  const int tid = threadIdx.x;
  const int lane = tid & 63, wid = tid >> 6;
  const int g = lane >> 4, c = lane & 15;
  const int wm = wid >> 1, wn = wid & 1;

  __shared__ alignas(16) u16 As[128 * 40];  // row stride 40 u16 = 80B (2-way max)
  __shared__ alignas(16) u16 Bs[128 * 40];

  f32x4 acc[4][4];
  #pragma unroll
  for (int i = 0; i < 4; ++i)
    #pragma unroll
    for (int j = 0; j < 4; ++j) acc[i][j] = f32x4{0.f, 0.f, 0.f, 0.f};

  const int srow = tid >> 1;
  const int sj = (tid & 1) * 16;     // elems
  const u16* Ag = A + (m0 + srow) * C_ + sj;
  const u16* Bg = Bw + (n0 + srow) * C_ + sj;
  u16* Al = As + srow * 40 + sj;
  u16* Bl = Bs + srow * 40 + sj;

  s16x8 a0 = *(const s16x8*)(Ag);
  s16x8 a1 = *(const s16x8*)(Ag + 8);
  s16x8 b0 = *(const s16x8*)(Bg);
  s16x8 b1 = *(const s16x8*)(Bg + 8);

  const int KT = C_ / 32;
  for (int kt = 0; kt < KT; ++kt) {
    __syncthreads();
    *(s16x8*)(Al) = a0; *(s16x8*)(Al + 8) = a1;
    *(s16x8*)(Bl) = b0; *(s16x8*)(Bl + 8) = b1;
    __syncthreads();
    if (kt + 1 < KT) {
      a0 = *(const s16x8*)(Ag + (kt + 1) * 32);
      a1 = *(const s16x8*)(Ag + (kt + 1) * 32 + 8);
      b0 = *(const s16x8*)(Bg + (kt + 1) * 32);
      b1 = *(const s16x8*)(Bg + (kt + 1) * 32 + 8);
    }
    s16x8 af[4], bf[4];
    #pragma unroll
    for (int mf = 0; mf < 4; ++mf)
      af[mf] = *(const s16x8*)(As + (wm * 64 + mf * 16 + c) * 40 + g * 8);
    #pragma unroll
    for (int nf = 0; nf < 4; ++nf)
      bf[nf] = *(const s16x8*)(Bs + (wn * 64 + nf * 16 + c) * 40 + g * 8);
    #pragma unroll
    for (int mf = 0; mf < 4; ++mf)
      #pragma unroll
      for (int nf = 0; nf < 4; ++nf)
        acc[mf][nf] = mfma16(af[mf], bf[nf], acc[mf][nf]);
  }

  float bv4[4];
  #pragma unroll
  for (int nf = 0; nf < 4; ++nf) bv4[nf] = bias[n0 + wn * 64 + nf * 16 + c];

  #pragma unroll
  for (int mf = 0; mf < 4; ++mf) {
    const int btb = m0 + wm * 64 + mf * 16 + g * 4;
    #pragma unroll
    for (int nf = 0; nf < 4; ++nf) {
      const int n = n0 + wn * 64 + nf * 16 + c;
      #pragma unroll
      for (int r = 0; r < 4; ++r) {
        float v = acc[mf][nf][r] + bv4[nf];
        const int row = btb + r;
        if (MODE == 1) {
          yout[row * C_ + n] = v;
        } else {
          if (n < 512) {
            const int hh = n >> 6, d = n & 63;
            const int bb = row >> 11, t = row & 2047;
            qp[((bb * H_ + hh) * T_ + t) * DKP + d] = f2b(v * 0.125f);
          } else if (n < 1024) {
            const int nn = n - 512;
            const int hh = nn >> 6, d = nn & 63;
            const int bb = row >> 11, t = row & 2047;
            kp[((bb * H_ + hh) * T_ + t) * DKP + d] = f2b(v);
          } else {
            vtmp[row * C_ + (n - 1024)] = f2b(v);
          }
        }
      }
    }
  }
}

// ---------------------------------------------------------------------------
// V transpose: Vtmp[bt][c] -> Vt[bh][80][T]; row 64 = ones (softmax-l column),
// rows 65..79 = zeros.
// ---------------------------------------------------------------------------
__global__ __launch_bounds__(256) void k_vtrans(const u16* __restrict__ vtmp,
                                                u16* __restrict__ vt)
{
  const int t0 = blockIdx.x * 64;
  const int bh = blockIdx.y;
  const int b = bh >> 3, h = bh & 7;
  const int tid = threadIdx.x;
  __shared__ alignas(16) u16 tile[64 * 72];
  #pragma unroll
  for (int it = 0; it < 2; ++it) {
    int task = tid + it * 256;
    int r = task >> 3, cj = task & 7;
    u16x8 v = *(const u16x8*)(vtmp + (b * T_ + t0 + r) * C_ + h * 64 + cj * 8);
    #pragma unroll
    for (int j = 0; j < 8; ++j) tile[(cj * 8 + j) * 72 + r] = v[j];
  }
  __syncthreads();
  #pragma unroll
  for (int it = 0; it < 2; ++it) {
    int task = tid + it * 256;
    int d = task >> 3, cj = task & 7;
    u16x8 o = *(const u16x8*)(tile + d * 72 + cj * 8);
    *(u16x8*)(vt + (bh * 80 + d) * T_ + t0 + cj * 8) = o;
  }
  if (tid < 128) {
    int d = 64 + (tid >> 3), cj = tid & 7;
    u16 val = (d == 64) ? (u16)0x3F80 : (u16)0;
    u16x8 o;
    #pragma unroll
    for (int j = 0; j < 8; ++j) o[j] = val;
    *(u16x8*)(vt + (bh * 80 + d) * T_ + t0 + cj * 8) = o;
  }
}

// ---------------------------------------------------------------------------
// Flash attention. Grid (16 qblk, 32 bh), 256 thr. Wave = 32 q-rows.
// Qp/Kp padded dk=96 carry the phase bias inside QK^T; Vt row 64 of ones
// accumulates the softmax denominator as acc column.
// ---------------------------------------------------------------------------
__global__ __launch_bounds__(256) void k_attn(
    const u16* __restrict__ qp, const u16* __restrict__ kp,
    const u16* __restrict__ vt, u16* __restrict__ ctxb)
{
  const int qblk = blockIdx.x, bh = blockIdx.y;
  const int b = bh >> 3, h = bh & 7;
  const int tid = threadIdx.x, wid = tid >> 6, lane = tid & 63;
  const int g = lane >> 4, c = lane & 15;

  __shared__ alignas(16) u16 Ks[32 * 104];   // 32 keys x 96 (+8 pad)
  __shared__ alignas(16) u16 Vs[80 * 40];    // 80 d x 32 t (+8 pad)
  __shared__ alignas(16) u16 Ps[4][32 * 40]; // per-wave P tile

  const int q0 = qblk * 128 + wid * 32;
  const u16* qpb = qp + (bh * T_ + q0) * DKP;
  s16x8 qfr[2][3];
  #pragma unroll
  for (int a = 0; a < 2; ++a)
    #pragma unroll
    for (int ks = 0; ks < 3; ++ks)
      qfr[a][ks] = *(const s16x8*)(qpb + (a * 16 + c) * DKP + ks * 32 + g * 8);

  f32x4 acc[2][5];
  #pragma unroll
  for (int a = 0; a < 2; ++a)
    #pragma unroll
    for (int df = 0; df < 5; ++df) acc[a][df] = f32x4{0.f, 0.f, 0.f, 0.f};
  float mrun[2][4];
  #pragma unroll
  for (int a = 0; a < 2; ++a)
    #pragma unroll
    for (int r = 0; r < 4; ++r) mrun[a][r] = -__builtin_inff();

  // staging maps (iter-invariant)
  const int r_k0 = tid / 12, j_k0 = tid % 12;
  const int r_k1 = (256 + tid) / 12, j_k1 = (256 + tid) % 12;
  const bool k2 = tid < 128;
  const u16* kpb = kp + (bh * T_) * DKP;
  u16* kl0 = Ks + r_k0 * 104 + j_k0 * 8;
  u16* kl1 = Ks + r_k1 * 104 + j_k1 * 8;
  const int ko0 = r_k0 * DKP + j_k0 * 8;
  const int ko1 = r_k1 * DKP + j_k1 * 8;

  const int r_v0 = tid >> 2, j_v0 = tid & 3;
  const bool v2 = tid < 64;
  const int r_v1 = 64 + (tid >> 2), j_v1 = tid & 3;
  const u16* vtb = vt + bh * 80 * T_;
  u16* vl0 = Vs + r_v0 * 40 + j_v0 * 8;
  u16* vl1 = Vs + r_v1 * 40 + j_v1 * 8;
  const int vo0 = r_v0 * T_ + j_v0 * 8;
  const int vo1 = r_v1 * T_ + j_v1 * 8;

  s16x8 kc0 = *(const s16x8*)(kpb + ko0);
  s16x8 kc1 = {}; if (k2) kc1 = *(const s16x8*)(kpb + ko1);
  s16x8 vc0 = *(const s16x8*)(vtb + vo0);
  s16x8 vc1 = {}; if (v2) vc1 = *(const s16x8*)(vtb + vo1);

  for (int kt = 0; kt < 64; ++kt) {
    __syncthreads();
    *(s16x8*)kl0 = kc0;
    if (k2) *(s16x8*)kl1 = kc1;
    *(s16x8*)vl0 = vc0;
    if (v2) *(s16x8*)vl1 = vc1;
    __syncthreads();
    if (kt < 63) {
      const int off = (kt + 1) * 32;
      kc0 = *(const s16x8*)(kpb + off * DKP + ko0);
      if (k2) kc1 = *(const s16x8*)(kpb + off * DKP + ko1);
      vc0 = *(const s16x8*)(vtb + off + vo0);
      if (v2) vc1 = *(const s16x8*)(vtb + off + vo1);
    }

    // QK^T (includes phase bias via pad cols)
    f32x4 s2[2][2];
    #pragma unroll
    for (int a = 0; a < 2; ++a)
      #pragma unroll
      for (int kf = 0; kf < 2; ++kf) s2[a][kf] = f32x4{0.f, 0.f, 0.f, 0.f};
    #pragma unroll
    for (int kf = 0; kf < 2; ++kf)
      #pragma unroll
      for (int ks = 0; ks < 3; ++ks) {
        s16x8 kfrag = *(const s16x8*)(Ks + (kf * 16 + c) * 104 + (ks * 4 + g) * 8);
        s2[0][kf] = mfma16(qfr[0][ks], kfrag, s2[0][kf]);
        s2[1][kf] = mfma16(qfr[1][ks], kfrag, s2[1][kf]);
      }

    // online softmax (row reduce over 16 lanes; l rides in V ones-column)
    #pragma unroll
    for (int a = 0; a < 2; ++a) {
      float p0[4], p1[4];
      #pragma unroll
      for (int r = 0; r < 4; ++r) {
        float v0 = s2[a][0][r], v1 = s2[a][1][r];
        float t = fmaxf(v0, v1);
        t = fmaxf(t, __shfl_xor(t, 1));
        t = fmaxf(t, __shfl_xor(t, 2));
        t = fmaxf(t, __shfl_xor(t, 4));
        t = fmaxf(t, __shfl_xor(t, 8));
        float mo = mrun[a][r];
        float mn = fmaxf(mo, t);
        mrun[a][r] = mn;
        float al = exp2f((mo - mn) * LOG2E);
        #pragma unroll
        for (int df = 0; df < 5; ++df) acc[a][df][r] *= al;
        p0[r] = exp2f((v0 - mn) * LOG2E);
        p1[r] = exp2f((v1 - mn) * LOG2E);
      }
      u16* pw = Ps[wid] + (a * 16 + g * 4) * 40 + c;
      #pragma unroll
      for (int r = 0; r < 4; ++r) {
        pw[r * 40] = f2b(p0[r]);
        pw[r * 40 + 16] = f2b(p1[r]);
      }
    }

    // PV (+ l in df index via ones row of Vt)
    s16x8 pf0 = *(const s16x8*)(Ps[wid] + c * 40 + g * 8);
    s16x8 pf1 = *(const s16x8*)(Ps[wid] + (16 + c) * 40 + g * 8);
    #pragma unroll
    for (int df = 0; df < 5; ++df) {
      s16x8 vfrag = *(const s16x8*)(Vs + (df * 16 + c) * 40 + g * 8);
      acc[0][df] = mfma16(pf0, vfrag, acc[0][df]);
      acc[1][df] = mfma16(pf1, vfrag, acc[1][df]);
    }
  }

  // epilogue: divide by l (acc[.][4], col 64, at lanes c==0) and store bf16
  #pragma unroll
  for (int a = 0; a < 2; ++a) {
    float linv[4];
    #pragma unroll
    for (int r = 0; r < 4; ++r) {
      float lv = __shfl(acc[a][4][r], lane & 48);
      linv[r] = 1.0f / lv;
    }
    const int trow = q0 + a * 16 + g * 4;
    u16* outp = ctxb + (b * T_ + trow) * C_ + h * 64;
    #pragma unroll
    for (int df = 0; df < 4; ++df)
      #pragma unroll
      for (int r = 0; r < 4; ++r)
        outp[r * C_ + df * 16 + c] = f2b(acc[a][df][r] * linv[r]);
  }
}

// ---------------------------------------------------------------------------
// Residual + LayerNorm: out = LN(yout + x) * g + b   (one wave per row)
// ---------------------------------------------------------------------------
__global__ __launch_bounds__(256) void k_ln(
    const float* __restrict__ yo, const float* __restrict__ x,
    const float* __restrict__ gg, const float* __restrict__ bb,
    float* __restrict__ out)
{
  const int row = blockIdx.x * 4 + (threadIdx.x >> 6);
  const int lane = threadIdx.x & 63;
  const float4* yp = (const float4*)(yo + row * C_);
  const float4* xp = (const float4*)(x + row * C_);
  float4 v[2];
  float s = 0.f, ss = 0.f;
  #pragma unroll
  for (int i = 0; i < 2; ++i) {
    float4 a = yp[lane * 2 + i];
    float4 xx = xp[lane * 2 + i];
    float4 w;
    w.x = a.x + xx.x; w.y = a.y + xx.y; w.z = a.z + xx.z; w.w = a.w + xx.w;
    v[i] = w;
    s += w.x + w.y + w.z + w.w;
    ss += w.x * w.x + w.y * w.y + w.z * w.z + w.w * w.w;
  }
  #pragma unroll
  for (int m = 1; m < 64; m <<= 1) {
    s += __shfl_xor(s, m);
    ss += __shfl_xor(ss, m);
  }
  const float mu = s * (1.0f / 512.0f);
  const float rs = rsqrtf(ss * (1.0f / 512.0f) - mu * mu + 1e-5f);
  const float4* gp = (const float4*)gg;
  const float4* bp = (const float4*)bb;
  float4* op = (float4*)(out + row * C_);
  #pragma unroll
  for (int i = 0; i < 2; ++i) {
    float4 gv = gp[lane * 2 + i], bv = bp[lane * 2 + i];
    float4 w = v[i], o;
    o.x = (w.x - mu) * rs * gv.x + bv.x;
    o.y = (w.y - mu) * rs * gv.y + bv.y;
    o.z = (w.z - mu) * rs * gv.z + bv.z;
    o.w = (w.w - mu) * rs * gv.w + bv.w;
    op[lane * 2 + i] = o;
  }
}

// ---------------------------------------------------------------------------
extern "C" void kernel_launch(void* const* d_in, const int* in_sizes, int n_in,
                              void* d_out, int out_size, void* d_ws, size_t ws_size,
                              hipStream_t stream)
{
  const float* x   = (const float*)d_in[0];
  const float* wqw = (const float*)d_in[1];
  const float* wqb = (const float*)d_in[2];
  const float* wkw = (const float*)d_in[3];
  const float* wkb = (const float*)d_in[4];
  const float* wvw = (const float*)d_in[5];
  const float* wvb = (const float*)d_in[6];
  const float* wow = (const float*)d_in[7];
  const float* wob = (const float*)d_in[8];
  const float* pb  = (const float*)d_in[9];
  const float* lng = (const float*)d_in[10];
  const float* lnb = (const float*)d_in[11];

  char* w = (char*)d_ws;
  u16*   xb   = (u16*)(w + 0);            //  8.39 MB
  u16*   wcat = (u16*)(w + 8388608);      //  1.57 MB
  u16*   wo16 = (u16*)(w + 9961472);      //  0.52 MB
  float* bcat = (float*)(w + 10485760);   //  6 KB
  u16*   qp   = (u16*)(w + 10491904);     // 12.58 MB  [bh][t][96]
  u16*   kp   = (u16*)(w + 23074816);     // 12.58 MB
  u16*   vtmp = (u16*)(w + 35657728);     //  8.39 MB
  u16*   vtq  = (u16*)(w + 44046336);     // 10.49 MB  [bh][80][2048]
  u16*   ctxb = (u16*)(w + 54532096);     //  8.39 MB  (end 62.9 MB)
  float* yout = (float*)(w + 10491904);   // 16.78 MB, aliases qp/kp (dead then)

  k_convert<<<4609, 256, 0, stream>>>(x, wqw, wkw, wvw, wow, wqb, wkb, wvb, pb,
                                      xb, wcat, wo16, bcat, qp, kp);
  k_gemm<0><<<dim3(12, 64), 256, 0, stream>>>(xb, wcat, bcat, qp, kp, vtmp, nullptr);
  k_vtrans<<<dim3(32, 32), 256, 0, stream>>>(vtmp, vtq);
  k_attn<<<dim3(16, 32), 256, 0, stream>>>(qp, kp, vtq, ctxb);
  k_gemm<1><<<dim3(4, 64), 256, 0, stream>>>(ctxb, wo16, wob, nullptr, nullptr, nullptr, yout);
  k_ln<<<2048, 256, 0, stream>>>(yout, x, lng, lnb, (float*)d_out);
}

// Round 3
// 235.576 us; speedup vs baseline: 1.3360x; 1.3360x over previous
//
#include <hip/hip_runtime.h>

typedef __attribute__((ext_vector_type(8))) short s16x8;
typedef __attribute__((ext_vector_type(8))) unsigned short u16x8;
typedef __attribute__((ext_vector_type(4))) float f32x4;
typedef unsigned short u16;
typedef unsigned int u32;

#define T_ 2048
#define C_ 512
#define H_ 8
#define DKP 96
#define LOG2E 1.44269504088896340736f
#define QSCALE 0.18033688011112042f  // 0.125 * log2(e)

__device__ __forceinline__ u16 f2b(float f) {
  u32 u = __float_as_uint(f);
  return (u16)((u + 0x7FFFu + ((u >> 16) & 1u)) >> 16);
}

__device__ __forceinline__ float b2f(u16 b) {
  return __uint_as_float(((u32)b) << 16);
}

__device__ __forceinline__ u16x8 cvt8(float4 a, float4 b) {
  u16x8 o;
  o[0] = f2b(a.x); o[1] = f2b(a.y); o[2] = f2b(a.z); o[3] = f2b(a.w);
  o[4] = f2b(b.x); o[5] = f2b(b.y); o[6] = f2b(b.z); o[7] = f2b(b.w);
  return o;
}

__device__ __forceinline__ f32x4 mfma16(s16x8 a, s16x8 b, f32x4 c) {
  return __builtin_amdgcn_mfma_f32_16x16x32_bf16(a, b, c, 0, 0, 0);
}

// ---------------------------------------------------------------------------
// Convert/pack: xb, Wcat(Wq|Wk|Wv), Wo16, bcat(fp32), Q pad cols (onehot q%3),
// K pad cols (bias[c][k%3] * log2e).
// ---------------------------------------------------------------------------
__global__ __launch_bounds__(256) void k_convert(
    const float* __restrict__ x,
    const float* __restrict__ wq, const float* __restrict__ wk,
    const float* __restrict__ wv, const float* __restrict__ wo,
    const float* __restrict__ bq, const float* __restrict__ bk,
    const float* __restrict__ bv, const float* __restrict__ pb,
    u16* __restrict__ xb, u16* __restrict__ wcat, u16* __restrict__ wo16,
    float* __restrict__ bcat, u16* __restrict__ qp, u16* __restrict__ kp)
{
  const int blk = blockIdx.x, tid = threadIdx.x;
  if (blk < 2048) {
    int i = blk * 2048 + tid * 8;
    float4 a = *(const float4*)(x + i);
    float4 b = *(const float4*)(x + i + 4);
    *(u16x8*)(xb + i) = cvt8(a, b);
  } else if (blk < 2432) {
    int bi = blk - 2048;
    const float* src; int off;
    if (bi < 128)      { src = wq; off = bi * 2048; }
    else if (bi < 256) { src = wk; off = (bi - 128) * 2048; }
    else               { src = wv; off = (bi - 256) * 2048; }
    int i = off + tid * 8;
    float4 a = *(const float4*)(src + i);
    float4 b = *(const float4*)(src + i + 4);
    *(u16x8*)(wcat + bi * 2048 + tid * 8) = cvt8(a, b);
  } else if (blk < 2560) {
    int i = (blk - 2432) * 2048 + tid * 8;
    float4 a = *(const float4*)(wo + i);
    float4 b = *(const float4*)(wo + i + 4);
    *(u16x8*)(wo16 + i) = cvt8(a, b);
  } else if (blk == 2560) {
    if (tid < 192) {
      int i = tid * 8;
      const float* src; int off;
      if (i < 512)       { src = bq; off = i; }
      else if (i < 1024) { src = bk; off = i - 512; }
      else               { src = bv; off = i - 1024; }
      *(float4*)(bcat + i)     = *(const float4*)(src + off);
      *(float4*)(bcat + i + 4) = *(const float4*)(src + off + 4);
    }
  } else if (blk < 3585) {
    int e = (blk - 2561) * 2048 + tid * 8;
    int row = e >> 5, cc = e & 31;
    int tp = (row & 2047) % 3;
    u16x8 o;
    #pragma unroll
    for (int j = 0; j < 8; ++j) {
      int cidx = cc + j;
      o[j] = (cidx < 3) ? ((tp == cidx) ? (u16)0x3F80 : (u16)0) : (u16)0;
    }
    *(u16x8*)(qp + row * DKP + 64 + cc) = o;
  } else {
    int e = (blk - 3585) * 2048 + tid * 8;
    int row = e >> 5, cc = e & 31;
    int tp = (row & 2047) % 3;
    u16x8 o;
    #pragma unroll
    for (int j = 0; j < 8; ++j) {
      int cidx = cc + j;
      o[j] = (cidx < 3) ? f2b(pb[cidx * 3 + tp] * LOG2E) : (u16)0;
    }
    *(u16x8*)(kp + row * DKP + 64 + cc) = o;
  }
}

// ---------------------------------------------------------------------------
// GEMM  C[m][n] = A[m][:] . B[n][:] + bias[n]   (A,B bf16 K-contig, K=512)
// MODE 0: QKV — Qp scaled by 0.125*log2e, Kp, Vtmp.   MODE 1: O-proj fp32.
// ---------------------------------------------------------------------------
template<int MODE>
__global__ __launch_bounds__(256) void k_gemm(
    const u16* __restrict__ A, const u16* __restrict__ Bw,
    const float* __restrict__ bias,
    u16* __restrict__ qp, u16* __restrict__ kp, u16* __restrict__ vtmp,
    float* __restrict__ yout)
{
  const int n0 = blockIdx.x * 128;
  const int m0 = blockIdx.y * 128;
  const int tid = threadIdx.x;
  const int lane = tid & 63, wid = tid >> 6;
  const int g = lane >> 4, c = lane & 15;
  const int wm = wid >> 1, wn = wid & 1;

  __shared__ alignas(16) u16 As[128 * 40];
  __shared__ alignas(16) u16 Bs[128 * 40];

  f32x4 acc[4][4];
  #pragma unroll
  for (int i = 0; i < 4; ++i)
    #pragma unroll
    for (int j = 0; j < 4; ++j) acc[i][j] = f32x4{0.f, 0.f, 0.f, 0.f};

  const int srow = tid >> 1;
  const int sj = (tid & 1) * 16;
  const u16* Ag = A + (m0 + srow) * C_ + sj;
  const u16* Bg = Bw + (n0 + srow) * C_ + sj;
  u16* Al = As + srow * 40 + sj;
  u16* Bl = Bs + srow * 40 + sj;

  s16x8 a0 = *(const s16x8*)(Ag);
  s16x8 a1 = *(const s16x8*)(Ag + 8);
  s16x8 b0 = *(const s16x8*)(Bg);
  s16x8 b1 = *(const s16x8*)(Bg + 8);

  const int KT = C_ / 32;
  for (int kt = 0; kt < KT; ++kt) {
    __syncthreads();
    *(s16x8*)(Al) = a0; *(s16x8*)(Al + 8) = a1;
    *(s16x8*)(Bl) = b0; *(s16x8*)(Bl + 8) = b1;
    __syncthreads();
    if (kt + 1 < KT) {
      a0 = *(const s16x8*)(Ag + (kt + 1) * 32);
      a1 = *(const s16x8*)(Ag + (kt + 1) * 32 + 8);
      b0 = *(const s16x8*)(Bg + (kt + 1) * 32);
      b1 = *(const s16x8*)(Bg + (kt + 1) * 32 + 8);
    }
    s16x8 af[4], bf[4];
    #pragma unroll
    for (int mf = 0; mf < 4; ++mf)
      af[mf] = *(const s16x8*)(As + (wm * 64 + mf * 16 + c) * 40 + g * 8);
    #pragma unroll
    for (int nf = 0; nf < 4; ++nf)
      bf[nf] = *(const s16x8*)(Bs + (wn * 64 + nf * 16 + c) * 40 + g * 8);
    #pragma unroll
    for (int mf = 0; mf < 4; ++mf)
      #pragma unroll
      for (int nf = 0; nf < 4; ++nf)
        acc[mf][nf] = mfma16(af[mf], bf[nf], acc[mf][nf]);
  }

  float bv4[4];
  #pragma unroll
  for (int nf = 0; nf < 4; ++nf) bv4[nf] = bias[n0 + wn * 64 + nf * 16 + c];

  #pragma unroll
  for (int mf = 0; mf < 4; ++mf) {
    const int btb = m0 + wm * 64 + mf * 16 + g * 4;
    #pragma unroll
    for (int nf = 0; nf < 4; ++nf) {
      const int n = n0 + wn * 64 + nf * 16 + c;
      #pragma unroll
      for (int r = 0; r < 4; ++r) {
        float v = acc[mf][nf][r] + bv4[nf];
        const int row = btb + r;
        if (MODE == 1) {
          yout[row * C_ + n] = v;
        } else {
          if (n < 512) {
            const int hh = n >> 6, d = n & 63;
            const int bb = row >> 11, t = row & 2047;
            qp[((bb * H_ + hh) * T_ + t) * DKP + d] = f2b(v * QSCALE);
          } else if (n < 1024) {
            const int nn = n - 512;
            const int hh = nn >> 6, d = nn & 63;
            const int bb = row >> 11, t = row & 2047;
            kp[((bb * H_ + hh) * T_ + t) * DKP + d] = f2b(v);
          } else {
            vtmp[row * C_ + (n - 1024)] = f2b(v);
          }
        }
      }
    }
  }
}

// ---------------------------------------------------------------------------
// V transpose: Vtmp[bt][c] -> Vt[bh][80][T] with keys PERMUTED within each
// 32-group: key k -> 2*(k&15) + (k>>4)  (matches attn's packed-P col order).
// Row 64 = ones (softmax-l), rows 65..79 = zeros (perm-invariant).
// ---------------------------------------------------------------------------
__global__ __launch_bounds__(256) void k_vtrans(const u16* __restrict__ vtmp,
                                                u16* __restrict__ vt)
{
  const int t0 = blockIdx.x * 64;
  const int bh = blockIdx.y;
  const int b = bh >> 3, h = bh & 7;
  const int tid = threadIdx.x;
  __shared__ alignas(16) u16 tile[64 * 72];
  #pragma unroll
  for (int it = 0; it < 2; ++it) {
    int task = tid + it * 256;
    int r = task >> 3, cj = task & 7;
    int pr = (r & 32) | (((r & 15) << 1) | ((r >> 4) & 1));
    u16x8 v = *(const u16x8*)(vtmp + (b * T_ + t0 + r) * C_ + h * 64 + cj * 8);
    #pragma unroll
    for (int j = 0; j < 8; ++j) tile[(cj * 8 + j) * 72 + pr] = v[j];
  }
  __syncthreads();
  #pragma unroll
  for (int it = 0; it < 2; ++it) {
    int task = tid + it * 256;
    int d = task >> 3, cj = task & 7;
    u16x8 o = *(const u16x8*)(tile + d * 72 + cj * 8);
    *(u16x8*)(vt + (bh * 80 + d) * T_ + t0 + cj * 8) = o;
  }
  if (tid < 128) {
    int d = 64 + (tid >> 3), cj = tid & 7;
    u16 val = (d == 64) ? (u16)0x3F80 : (u16)0;
    u16x8 o;
    #pragma unroll
    for (int j = 0; j < 8; ++j) o[j] = val;
    *(u16x8*)(vt + (bh * 80 + d) * T_ + t0 + cj * 8) = o;
  }
}

// ---------------------------------------------------------------------------
// Flash attention, fixed-max softmax (p = exp2(s), log2e folded upstream).
// Grid: 1024 linear blocks -> (bh, z, qblk), XCD-grouped. KV-split z in {0,1}.
// Writes unnormalized bf16 ctx partials (pc0: z=0, pc1: z=1) + fp32 l partials.
// ---------------------------------------------------------------------------
__global__ __launch_bounds__(256) void k_attn(
    const u16* __restrict__ qp, const u16* __restrict__ kp,
    const u16* __restrict__ vt, u16* __restrict__ pc0, u16* __restrict__ pc1,
    float* __restrict__ pl)
{
  const int lid = blockIdx.x;
  const int xcd = lid & 7, j = lid >> 3;
  const int gsel = j >> 4, qblk = j & 15;
  const int bhz = xcd * 8 + gsel;
  const int bh = bhz >> 1, z = bhz & 1;

  const int tid = threadIdx.x, wid = tid >> 6, lane = tid & 63;
  const int g = lane >> 4, c = lane & 15;

  __shared__ alignas(16) u16 Ks[32 * 104];
  __shared__ alignas(16) u16 Vs[80 * 40];
  __shared__ alignas(16) u16 Ps[4][32 * 40];

  const int q0 = qblk * 128 + wid * 32;
  const u16* qpb = qp + (bh * T_ + q0) * DKP;
  s16x8 qfr[2][3];
  #pragma unroll
  for (int a = 0; a < 2; ++a)
    #pragma unroll
    for (int ks = 0; ks < 3; ++ks)
      qfr[a][ks] = *(const s16x8*)(qpb + (a * 16 + c) * DKP + ks * 32 + g * 8);

  f32x4 acc[2][5];
  #pragma unroll
  for (int a = 0; a < 2; ++a)
    #pragma unroll
    for (int df = 0; df < 5; ++df) acc[a][df] = f32x4{0.f, 0.f, 0.f, 0.f};

  // staging maps (iter-invariant)
  const int r_k0 = tid / 12, j_k0 = tid % 12;
  const int r_k1 = (256 + tid) / 12, j_k1 = (256 + tid) % 12;
  const bool k2 = tid < 128;
  const u16* kpb = kp + (bh * T_ + z * 1024) * DKP;
  u16* kl0 = Ks + r_k0 * 104 + j_k0 * 8;
  u16* kl1 = Ks + r_k1 * 104 + j_k1 * 8;
  const int ko0 = r_k0 * DKP + j_k0 * 8;
  const int ko1 = r_k1 * DKP + j_k1 * 8;

  const int r_v0 = tid >> 2, j_v0 = tid & 3;
  const bool v2 = tid < 64;
  const int r_v1 = 64 + (tid >> 2), j_v1 = tid & 3;
  const u16* vtb = vt + bh * 80 * T_ + z * 1024;
  u16* vl0 = Vs + r_v0 * 40 + j_v0 * 8;
  u16* vl1 = Vs + r_v1 * 40 + j_v1 * 8;
  const int vo0 = r_v0 * T_ + j_v0 * 8;
  const int vo1 = r_v1 * T_ + j_v1 * 8;

  s16x8 kc0 = *(const s16x8*)(kpb + ko0);
  s16x8 kc1 = {}; if (k2) kc1 = *(const s16x8*)(kpb + ko1);
  s16x8 vc0 = *(const s16x8*)(vtb + vo0);
  s16x8 vc1 = {}; if (v2) vc1 = *(const s16x8*)(vtb + vo1);

  for (int kt = 0; kt < 32; ++kt) {
    __syncthreads();
    *(s16x8*)kl0 = kc0;
    if (k2) *(s16x8*)kl1 = kc1;
    *(s16x8*)vl0 = vc0;
    if (v2) *(s16x8*)vl1 = vc1;
    __syncthreads();
    if (kt < 31) {
      const int off = (kt + 1) * 32;
      kc0 = *(const s16x8*)(kpb + off * DKP + ko0);
      if (k2) kc1 = *(const s16x8*)(kpb + off * DKP + ko1);
      vc0 = *(const s16x8*)(vtb + off + vo0);
      if (v2) vc1 = *(const s16x8*)(vtb + off + vo1);
    }

    // QK^T (phase bias + log2e scaling baked into Qp/Kp)
    f32x4 s2[2][2];
    #pragma unroll
    for (int a = 0; a < 2; ++a)
      #pragma unroll
      for (int kf = 0; kf < 2; ++kf) s2[a][kf] = f32x4{0.f, 0.f, 0.f, 0.f};
    #pragma unroll
    for (int kf = 0; kf < 2; ++kf)
      #pragma unroll
      for (int ks = 0; ks < 3; ++ks) {
        s16x8 kfrag = *(const s16x8*)(Ks + (kf * 16 + c) * 104 + (ks * 4 + g) * 8);
        s2[0][kf] = mfma16(qfr[0][ks], kfrag, s2[0][kf]);
        s2[1][kf] = mfma16(qfr[1][ks], kfrag, s2[1][kf]);
      }

    // fixed-max softmax: p = 2^s, packed (kf0,kf1) -> one u32 (interleaved
    // key order, matches permuted V rows). No max-tracking, no rescale.
    #pragma unroll
    for (int a = 0; a < 2; ++a) {
      u32* pw = (u32*)(Ps[wid] + (a * 16 + g * 4) * 40) + c;
      #pragma unroll
      for (int r = 0; r < 4; ++r) {
        u32 b0 = __float_as_uint(exp2f(s2[a][0][r]));
        u32 b1 = __float_as_uint(exp2f(s2[a][1][r]));
        pw[r * 20] = ((b0 + 0x8000u) >> 16) | (((b1 + 0x8000u) >> 16) << 16);
      }
    }

    // PV (+ l via ones row of Vt)
    s16x8 pf0 = *(const s16x8*)(Ps[wid] + c * 40 + g * 8);
    s16x8 pf1 = *(const s16x8*)(Ps[wid] + (16 + c) * 40 + g * 8);
    #pragma unroll
    for (int df = 0; df < 5; ++df) {
      s16x8 vfrag = *(const s16x8*)(Vs + (df * 16 + c) * 40 + g * 8);
      acc[0][df] = mfma16(pf0, vfrag, acc[0][df]);
      acc[1][df] = mfma16(pf1, vfrag, acc[1][df]);
    }
  }

  // store unnormalized partials: ctx bf16 [bh][t][64] per split, l fp32
  u16* pcz = z ? pc1 : pc0;
  float* plz = pl + z * 65536;
  #pragma unroll
  for (int a = 0; a < 2; ++a) {
    #pragma unroll
    for (int r = 0; r < 4; ++r) {
      const int trow = q0 + a * 16 + g * 4 + r;
      u16* outp = pcz + ((size_t)bh * T_ + trow) * 64;
      #pragma unroll
      for (int df = 0; df < 4; ++df)
        outp[df * 16 + c] = f2b(acc[a][df][r]);
      if (c == 0) plz[bh * T_ + trow] = acc[a][4][r];
    }
  }
}

// ---------------------------------------------------------------------------
// Combine KV-split partials: ctx = (c0+c1)/(l0+l1), write bf16 [b][t][h*64+d]
// ---------------------------------------------------------------------------
__global__ __launch_bounds__(256) void k_combine(
    const u16* __restrict__ pc0, const u16* __restrict__ pc1,
    const float* __restrict__ pl, u16* __restrict__ ctxb)
{
  const int gid = blockIdx.x * 256 + threadIdx.x;
  const int row = gid >> 3;            // bh*2048 + t
  const int dj = (gid & 7) * 8;
  const u16x8 c0 = *(const u16x8*)(pc0 + (size_t)row * 64 + dj);
  const u16x8 c1 = *(const u16x8*)(pc1 + (size_t)row * 64 + dj);
  const float inv = 1.0f / (pl[row] + pl[65536 + row]);
  u16x8 o;
  #pragma unroll
  for (int j = 0; j < 8; ++j)
    o[j] = f2b((b2f(c0[j]) + b2f(c1[j])) * inv);
  const int bh = row >> 11, t = row & 2047;
  const int b = bh >> 3, h = bh & 7;
  *(u16x8*)(ctxb + ((size_t)(b * T_ + t)) * C_ + h * 64 + dj) = o;
}

// ---------------------------------------------------------------------------
// Residual + LayerNorm
// ---------------------------------------------------------------------------
__global__ __launch_bounds__(256) void k_ln(
    const float* __restrict__ yo, const float* __restrict__ x,
    const float* __restrict__ gg, const float* __restrict__ bb,
    float* __restrict__ out)
{
  const int row = blockIdx.x * 4 + (threadIdx.x >> 6);
  const int lane = threadIdx.x & 63;
  const float4* yp = (const float4*)(yo + row * C_);
  const float4* xp = (const float4*)(x + row * C_);
  float4 v[2];
  float s = 0.f, ss = 0.f;
  #pragma unroll
  for (int i = 0; i < 2; ++i) {
    float4 a = yp[lane * 2 + i];
    float4 xx = xp[lane * 2 + i];
    float4 w;
    w.x = a.x + xx.x; w.y = a.y + xx.y; w.z = a.z + xx.z; w.w = a.w + xx.w;
    v[i] = w;
    s += w.x + w.y + w.z + w.w;
    ss += w.x * w.x + w.y * w.y + w.z * w.z + w.w * w.w;
  }
  #pragma unroll
  for (int m = 1; m < 64; m <<= 1) {
    s += __shfl_xor(s, m);
    ss += __shfl_xor(ss, m);
  }
  const float mu = s * (1.0f / 512.0f);
  const float rs = rsqrtf(ss * (1.0f / 512.0f) - mu * mu + 1e-5f);
  const float4* gp = (const float4*)gg;
  const float4* bp = (const float4*)bb;
  float4* op = (float4*)(out + row * C_);
  #pragma unroll
  for (int i = 0; i < 2; ++i) {
    float4 gv = gp[lane * 2 + i], bv = bp[lane * 2 + i];
    float4 w = v[i], o;
    o.x = (w.x - mu) * rs * gv.x + bv.x;
    o.y = (w.y - mu) * rs * gv.y + bv.y;
    o.z = (w.z - mu) * rs * gv.z + bv.z;
    o.w = (w.w - mu) * rs * gv.w + bv.w;
    op[lane * 2 + i] = o;
  }
}

// ---------------------------------------------------------------------------
extern "C" void kernel_launch(void* const* d_in, const int* in_sizes, int n_in,
                              void* d_out, int out_size, void* d_ws, size_t ws_size,
                              hipStream_t stream)
{
  const float* x   = (const float*)d_in[0];
  const float* wqw = (const float*)d_in[1];
  const float* wqb = (const float*)d_in[2];
  const float* wkw = (const float*)d_in[3];
  const float* wkb = (const float*)d_in[4];
  const float* wvw = (const float*)d_in[5];
  const float* wvb = (const float*)d_in[6];
  const float* wow = (const float*)d_in[7];
  const float* wob = (const float*)d_in[8];
  const float* pb  = (const float*)d_in[9];
  const float* lng = (const float*)d_in[10];
  const float* lnb = (const float*)d_in[11];

  char* w = (char*)d_ws;
  u16*   xb   = (u16*)(w + 0);            //  8.39 MB  -> reused as pc0 (z=0)
  u16*   wcat = (u16*)(w + 8388608);      //  1.57 MB  -> reused as pl (0.52 MB)
  u16*   wo16 = (u16*)(w + 9961472);      //  0.52 MB  (live until k_gemm<1>)
  float* bcat = (float*)(w + 10485760);   //  6 KB
  u16*   qp   = (u16*)(w + 10491904);     // 12.58 MB  [bh][t][96]
  u16*   kp   = (u16*)(w + 23074816);     // 12.58 MB
  u16*   vtmp = (u16*)(w + 35657728);     //  8.39 MB  -> reused as pc1 (z=1)
  u16*   vtq  = (u16*)(w + 44046336);     // 10.49 MB  [bh][80][2048] (perm keys)
  u16*   ctxb = (u16*)(w + 54532096);     //  8.39 MB  (end 62.9 MB)
  float* yout = (float*)(w + 10491904);   // 16.78 MB, aliases qp/kp (dead then)
  u16*   pc0  = xb;                       // partial ctx split 0
  u16*   pc1  = vtmp;                     // partial ctx split 1
  float* pl   = (float*)wcat;             // partial l: 2 x 65536 f32

  k_convert<<<4609, 256, 0, stream>>>(x, wqw, wkw, wvw, wow, wqb, wkb, wvb, pb,
                                      xb, wcat, wo16, bcat, qp, kp);
  k_gemm<0><<<dim3(12, 64), 256, 0, stream>>>(xb, wcat, bcat, qp, kp, vtmp, nullptr);
  k_vtrans<<<dim3(32, 32), 256, 0, stream>>>(vtmp, vtq);
  k_attn<<<1024, 256, 0, stream>>>(qp, kp, vtq, pc0, pc1, pl);
  k_combine<<<2048, 256, 0, stream>>>(pc0, pc1, pl, ctxb);
  k_gemm<1><<<dim3(4, 64), 256, 0, stream>>>(ctxb, wo16, wob, nullptr, nullptr, nullptr, yout);
  k_ln<<<2048, 256, 0, stream>>>(yout, x, lng, lnb, (float*)d_out);
}